// Round 14
// baseline (84.584 us; speedup 1.0000x reference)
//
#include <hip/hip_runtime.h>

// ---------------------------------------------------------------------------
// PANet disparity head — TWO-kernel pipeline for MI355X (gfx950).
//
// K1 panet_encode (R9-proven): encoder (x,y -> bf16 xf,yf in ws) + wd packed
//   as 400B-stride LDS image + bd*log2e.
// K2 panet_corr (R14 = R13 minus two defects):
//   * R13 defect 1 (spill, 31MB scratch @ VGPR=128): ks unroll 4 kept 16
//     in-flight b128 dests (64 regs) + useless bdr hoist (32 regs).
//     Fix: unroll 2, inline bd reads. Live set ~112 regs.
//   * R13 defect 2 (zero pipe overlap: MFMA 15 + VALU 19 + DS 30 = 64 ~ dur):
//     all 8 waves leave the barrier in phase; shared DS pipe re-syncs them
//     (convoy). Fix: stagger — wave w starts its s-loop at (w%3) and rotates.
//     Valid: no-max online accumulation is commutative.
//   * Everything else identical to R13: full wd + 8-copy hankel + bd in one
//     89KB dynamic-LDS block, ONE barrier, no-max softmax (R12-validated),
//     A stride-400 (R8), B 8-copy 16B-aligned (R10), both operands LDS
//     (R11/R12 falsified VMEM operands at this occupancy).
// ---------------------------------------------------------------------------

typedef __attribute__((ext_vector_type(8)))  __bf16 bf16x8;
typedef __attribute__((ext_vector_type(4)))  float  f32x4;
typedef __attribute__((ext_vector_type(16))) float  f32x16;

#define MFMA32(a,b,c) __builtin_amdgcn_mfma_f32_32x32x16_bf16((a),(b),(c),0,0,0)
#define MFMA16(a,b,c) __builtin_amdgcn_mfma_f32_16x16x32_bf16((a),(b),(c),0,0,0)

constexpr int WW  = 512;
constexpr int HW  = 256 * 512;      // 131072
constexpr int CHW = 32 * HW;        // 4194304
constexpr float LOG2E = 1.4426950408889634f;

// d_ws layout (R9):
constexpr size_t XFB_OFF = 0;                   // bf16 [2 img][512 row][512 w]
constexpr int    STB     = 25600;               // 64 rows x 400 B
constexpr size_t WDP_OFF = 2 * 262144 * 2;      // 1048576: wd image 3*25600
constexpr size_t BDP_OFF = WDP_OFF + 3 * STB;   // f32[192] = bd * LOG2E

// ---------------------------------------------------------------- K1
__global__ __launch_bounds__(512)
void panet_encode(const float* __restrict__ gx,  const float* __restrict__ gy,
                  const float* __restrict__ gw1, const float* __restrict__ gb1,
                  const float* __restrict__ gw2, const float* __restrict__ gb2,
                  const float* __restrict__ gw3, const float* __restrict__ gb3,
                  const float* __restrict__ gwd, const float* __restrict__ gbd,
                  char* __restrict__ ws)
{
  const int blk = blockIdx.x;
  const int tid = threadIdx.x;

  if (blk >= 1024) {                          // ---- packer blocks 1024..1039
    const int pi = blk - 1024;                // 16 blocks, 12 o-rows each
    unsigned short* wdp = (unsigned short*)(ws + WDP_OFF);
    for (int idx = tid; idx < 12 * 200; idx += 512) {  // 200 ushort per 400B row
      const int oo = idx / 200;
      const int k  = idx - oo * 200;
      const int o  = 12 * pi + oo;
      unsigned short v = 0;
      if (k < 192) v = __builtin_bit_cast(unsigned short, (__bf16)gwd[o * 192 + k]);
      wdp[(o >> 6) * 12800 + (o & 63) * 200 + k] = v;
    }
    if (pi == 0) {
      float* bdp = (float*)(ws + BDP_OFF);
      if (tid < 192) bdp[tid] = gbd[tid] * LOG2E;
    }
    return;
  }

  // ---- encoder: blk -> (t = image, bh). Proven R3..R13 body.
  const int t    = blk >> 9;
  const int bh   = blk & 511;
  const int lane = tid & 63;
  const int m    = lane & 15;
  const int g    = lane >> 4;
  const int wid  = tid >> 6;

  bf16x8 A1[4], A2[2][2];
  f32x4  bias1[4], bias2[2], w3v[2];
  #pragma unroll
  for (int Mt = 0; Mt < 4; ++Mt) {
    const float* p = gw1 + (16 * Mt + m) * 32 + 4 * g;
    const f32x4 u0 = *(const f32x4*)p;
    const f32x4 u1 = *(const f32x4*)(p + 16);
    #pragma unroll
    for (int j = 0; j < 4; ++j) { A1[Mt][j] = (__bf16)u0[j]; A1[Mt][j + 4] = (__bf16)u1[j]; }
    bias1[Mt] = *(const f32x4*)(gb1 + 16 * Mt + 4 * g);
  }
  #pragma unroll
  for (int Mt = 0; Mt < 2; ++Mt) {
    #pragma unroll
    for (int s = 0; s < 2; ++s) {
      const float* p = gw2 + (16 * Mt + m) * 64 + 32 * s + 4 * g;
      const f32x4 u0 = *(const f32x4*)p;
      const f32x4 u1 = *(const f32x4*)(p + 16);
      #pragma unroll
      for (int j = 0; j < 4; ++j) { A2[Mt][s][j] = (__bf16)u0[j]; A2[Mt][s][j + 4] = (__bf16)u1[j]; }
    }
    bias2[Mt] = *(const f32x4*)(gb2 + 16 * Mt + 4 * g);
    w3v[Mt]   = *(const f32x4*)(gw3 + 16 * Mt + 4 * g);
  }
  const float b3s = gb3[0];
  const f32x4 zf4 = {0.f, 0.f, 0.f, 0.f};
  const float* base = (t ? gy : gx) + (bh >> 8) * CHW + (bh & 255) * WW;
  unsigned short* xfb = (unsigned short*)(ws + XFB_OFF) + t * 262144 + bh * 512;

  for (int u = wid; u < 32; u += 8) {
    const int w0 = u << 4;
    const float* src = base + w0 + m;

    bf16x8 B1;
    #pragma unroll
    for (int j = 0; j < 8; ++j) {
      const int c = 16 * (j >> 2) + 4 * g + (j & 3);
      B1[j] = (__bf16)fmaxf(src[c * HW], 0.f);
    }
    f32x4 acc1[4];
    #pragma unroll
    for (int Mt = 0; Mt < 4; ++Mt) acc1[Mt] = MFMA16(A1[Mt], B1, zf4);

    bf16x8 B2[2];
    #pragma unroll
    for (int s = 0; s < 2; ++s) {
      #pragma unroll
      for (int j = 0; j < 4; ++j) {
        B2[s][j]     = (__bf16)fmaxf(acc1[2 * s][j]     + bias1[2 * s][j],     0.f);
        B2[s][j + 4] = (__bf16)fmaxf(acc1[2 * s + 1][j] + bias1[2 * s + 1][j], 0.f);
      }
    }
    f32x4 acc2[2];
    #pragma unroll
    for (int Mt = 0; Mt < 2; ++Mt)
      acc2[Mt] = MFMA16(A2[Mt][1], B2[1], MFMA16(A2[Mt][0], B2[0], zf4));

    float s3 = 0.f;
    #pragma unroll
    for (int Mt = 0; Mt < 2; ++Mt)
      #pragma unroll
      for (int r = 0; r < 4; ++r)
        s3 += w3v[Mt][r] * fmaxf(acc2[Mt][r] + bias2[Mt][r], 0.f);
    s3 += __shfl_xor(s3, 16);
    s3 += __shfl_xor(s3, 32);
    const float val = fmaxf(s3 + b3s, 0.f);

    if (lane < 16)
      xfb[w0 + m] = __builtin_bit_cast(unsigned short, (__bf16)val);
  }
}

// ---------------------------------------------------------------- K2
constexpr int CPS    = 1424;                  // hankel copy stride (bytes)
constexpr int K2_HK  = 76800;                 // after full wd image
constexpr int K2_BD  = K2_HK + 8 * CPS;       // 88192: f32[192]
constexpr int K2_LDS = K2_BD + 768;           // 88960 B dynamic

__global__ __launch_bounds__(512)
void panet_corr(const char* __restrict__ ws, float* __restrict__ gout)
{
  extern __shared__ __align__(16) char lds[];
  const int blk  = blockIdx.x;                // dir*512 + bh
  const int dir  = blk >> 9;
  const int bh   = blk & 511;
  const int tid  = threadIdx.x;
  const int lane = tid & 63;
  const int l31  = lane & 31;
  const int h    = lane >> 5;                 // lane half
  const int wid  = tid >> 6;                  // 8 waves, 64 cols each

  const unsigned short* xfbu = (const unsigned short*)(ws + XFB_OFF);
  const unsigned short* hs = xfbu + (dir ? 262144 : 0) + bh * 512;  // hankel src
  const unsigned short* ss = xfbu + (dir ? 0 : 262144) + bh * 512;  // scale src

  // ---- stage wd image + bd; build 8-copy hankel (zeros beyond 511)
  {
    const f32x4* src = (const f32x4*)(ws + WDP_OFF);
    f32x4* dst = (f32x4*)lds;
    #pragma unroll 5
    for (int i = tid; i < 4800; i += 512) dst[i] = src[i];
    if (tid < 192)
      ((float*)(lds + K2_BD))[tid] = ((const float*)(ws + BDP_OFF))[tid];
  }
  for (int e = tid; e < 712; e += 512) {
    #pragma unroll
    for (int c = 0; c < 8; ++c) {
      const int j = e + c;
      unsigned short v = 0;
      if (j <= 511) v = hs[dir ? (511 - j) : j];
      ((unsigned short*)(lds + K2_HK + c * CPS))[e] = v;
    }
  }
  __syncthreads();                             // the ONLY barrier

  // per-lane B bases + scales (2 col-tiles of 32; 64 cols per wave)
  const char* bptr[2]; float sc[2];
  #pragma unroll
  for (int ct = 0; ct < 2; ++ct) {
    const int col = wid * 64 + ct * 32 + l31;
    const int I0  = dir ? (511 - col) : col;
    const int cc  = I0 & 7;
    bptr[ct] = lds + K2_HK + cc * CPS + 2 * (I0 - cc) + 16 * h;
    sc[ct]  = LOG2E * __builtin_bit_cast(float, (unsigned)ss[col] << 16);
  }

  float stS0 = 0.f, stS1 = 0.f, stW0 = 0.f, stW1 = 0.f;

  int s = wid % 3;                             // stagger: de-convoy the waves
  for (int si = 0; si < 3; ++si) {             // 3 x 64 wd rows (rotated order)
    const char* abase = lds + (64 * s + l31) * 400 + 16 * h;
    f32x16 a00 = {0}, a01 = {0}, a10 = {0}, a11 = {0};
    #pragma unroll 2
    for (int ks = 0; ks < 12; ++ks) {          // K = 12*16 = 192
      const bf16x8 af0 = *(const bf16x8*)(abase + 32 * ks);
      const bf16x8 af1 = *(const bf16x8*)(abase + 12800 + 32 * ks);
      const bf16x8 bf0 = *(const bf16x8*)(bptr[0] + 32 * ks);
      const bf16x8 bf1 = *(const bf16x8*)(bptr[1] + 32 * ks);
      a00 = MFMA32(af0, bf0, a00);
      a01 = MFMA32(af0, bf1, a01);
      a10 = MFMA32(af1, bf0, a10);
      a11 = MFMA32(af1, bf1, a11);
    }

    // NO-max softmax accumulation (exp2 domain; logits bounded), inline bd
    const float obase = (float)(64 * s + 4 * h);
    #pragma unroll
    for (int ct = 0; ct < 2; ++ct) {
      float ls0 = 0.f, ls1 = 0.f, lw0 = 0.f, lw1 = 0.f;
      #pragma unroll
      for (int q = 0; q < 4; ++q) {
        const f32x4 bd0 = *(const f32x4*)(lds + K2_BD + (64 * s + 8 * q + 4 * h) * 4);
        const f32x4 bd1 = *(const f32x4*)(lds + K2_BD + (64 * s + 8 * q + 4 * h + 32) * 4);
        #pragma unroll
        for (int r = 0; r < 4; ++r) {
          const int i = 4 * q + r;
          const float L0 = fmaf(sc[ct], (ct ? a01 : a00)[i], bd0[r]);
          const float L1 = fmaf(sc[ct], (ct ? a11 : a10)[i], bd1[r]);
          const float p0 = __builtin_amdgcn_exp2f(L0);
          const float p1 = __builtin_amdgcn_exp2f(L1);
          const float c  = (float)(r + 8 * q);          // o - obase (rt=0)
          ls0 += p0;  ls1 += p1;
          lw0 = fmaf(c, p0, lw0);
          lw1 = fmaf(c + 32.f, p1, lw1);
        }
      }
      const float ls = ls0 + ls1;
      const float lw = fmaf(obase, ls, lw0 + lw1);
      if (ct == 0) { stS0 += ls; stW0 += lw; }
      else         { stS1 += ls; stW1 += lw; }
    }

    s = (s == 2) ? 0 : (s + 1);
  }

  // combine the two lane-halves (o split by h) and write
  float* outp = gout + dir * 262144 + bh * 512;
  #pragma unroll
  for (int ct = 0; ct < 2; ++ct) {
    float sr = ct ? stS1 : stS0;
    float wr = ct ? stW1 : stW0;
    sr += __shfl_xor(sr, 32);
    wr += __shfl_xor(wr, 32);
    if (lane < 32) outp[wid * 64 + ct * 32 + l31] = wr / sr;
  }
}

extern "C" void kernel_launch(void* const* d_in, const int* in_sizes, int n_in,
                              void* d_out, int out_size, void* d_ws, size_t ws_size,
                              hipStream_t stream) {
  const float* x  = (const float*)d_in[0];
  const float* y  = (const float*)d_in[1];
  const float* w1 = (const float*)d_in[2];
  const float* b1 = (const float*)d_in[3];
  const float* w2 = (const float*)d_in[4];
  const float* b2 = (const float*)d_in[5];
  const float* w3 = (const float*)d_in[6];
  const float* b3 = (const float*)d_in[7];
  const float* wd = (const float*)d_in[8];
  const float* bd = (const float*)d_in[9];
  char* ws = (char*)d_ws;

  (void)hipFuncSetAttribute((const void*)panet_corr,
                            hipFuncAttributeMaxDynamicSharedMemorySize, K2_LDS);
  panet_encode<<<1040, 512, 0, stream>>>(x, y, w1, b1, w2, b2, w3, b3, wd, bd, ws);
  panet_corr<<<1024, 512, K2_LDS, stream>>>(ws, (float*)d_out);
}

// Round 15
// 81.365 us; speedup vs baseline: 1.0396x; 1.0396x over previous
//
#include <hip/hip_runtime.h>

// ---------------------------------------------------------------------------
// PANet disparity head — TWO-kernel pipeline for MI355X (gfx950).
//
// K1 panet_encode (R9-proven): encoder (x,y -> bf16 xf,yf in ws) + wd packed
//   as 400B-stride LDS image + bd*log2e.
// K2 panet_corr (R15 = R13 with STATIC LDS):
//   * The 14-round VGPR mystery, solved: with DYNAMIC LDS the allocator
//     assumes 4 waves/SIMD -> hard 128-reg cap -> every >128 live set spilled
//     (R1/R2/R13/R14). With STATIC LDS it computes real occupancy: R12's
//     77.8KB static got 224 regs. At our pinned 2 waves/SIMD, 256 regs/wave
//     are free (m69 steps: 64/128/256).
//   * So: __shared__ char[88960] (static; >64KB statics compile on gfx950 —
//     R12 proved 77824). One block/CU, 8 waves, 256-reg budget, no spill.
//   * Rest identical to R13: full wd + 8-copy hankel + bd in LDS, ONE
//     barrier then free-running waves, no-max softmax (R12-validated
//     numerics), A stride-400 conflict-free (R8), B 8-copy 16B-aligned (R10).
//   * Stagger dropped (R14: no benefit, extra pressure). ks unroll 4 + bd
//     hoist reinstated (affordable under 256 regs; -14% DS instr).
// ---------------------------------------------------------------------------

typedef __attribute__((ext_vector_type(8)))  __bf16 bf16x8;
typedef __attribute__((ext_vector_type(4)))  float  f32x4;
typedef __attribute__((ext_vector_type(16))) float  f32x16;

#define MFMA32(a,b,c) __builtin_amdgcn_mfma_f32_32x32x16_bf16((a),(b),(c),0,0,0)
#define MFMA16(a,b,c) __builtin_amdgcn_mfma_f32_16x16x32_bf16((a),(b),(c),0,0,0)

constexpr int WW  = 512;
constexpr int HW  = 256 * 512;      // 131072
constexpr int CHW = 32 * HW;        // 4194304
constexpr float LOG2E = 1.4426950408889634f;

// d_ws layout (R9):
constexpr size_t XFB_OFF = 0;                   // bf16 [2 img][512 row][512 w]
constexpr int    STB     = 25600;               // 64 rows x 400 B
constexpr size_t WDP_OFF = 2 * 262144 * 2;      // 1048576: wd image 3*25600
constexpr size_t BDP_OFF = WDP_OFF + 3 * STB;   // f32[192] = bd * LOG2E

// ---------------------------------------------------------------- K1
__global__ __launch_bounds__(512)
void panet_encode(const float* __restrict__ gx,  const float* __restrict__ gy,
                  const float* __restrict__ gw1, const float* __restrict__ gb1,
                  const float* __restrict__ gw2, const float* __restrict__ gb2,
                  const float* __restrict__ gw3, const float* __restrict__ gb3,
                  const float* __restrict__ gwd, const float* __restrict__ gbd,
                  char* __restrict__ ws)
{
  const int blk = blockIdx.x;
  const int tid = threadIdx.x;

  if (blk >= 1024) {                          // ---- packer blocks 1024..1039
    const int pi = blk - 1024;                // 16 blocks, 12 o-rows each
    unsigned short* wdp = (unsigned short*)(ws + WDP_OFF);
    for (int idx = tid; idx < 12 * 200; idx += 512) {  // 200 ushort per 400B row
      const int oo = idx / 200;
      const int k  = idx - oo * 200;
      const int o  = 12 * pi + oo;
      unsigned short v = 0;
      if (k < 192) v = __builtin_bit_cast(unsigned short, (__bf16)gwd[o * 192 + k]);
      wdp[(o >> 6) * 12800 + (o & 63) * 200 + k] = v;
    }
    if (pi == 0) {
      float* bdp = (float*)(ws + BDP_OFF);
      if (tid < 192) bdp[tid] = gbd[tid] * LOG2E;
    }
    return;
  }

  // ---- encoder: blk -> (t = image, bh). Proven R3..R14 body.
  const int t    = blk >> 9;
  const int bh   = blk & 511;
  const int lane = tid & 63;
  const int m    = lane & 15;
  const int g    = lane >> 4;
  const int wid  = tid >> 6;

  bf16x8 A1[4], A2[2][2];
  f32x4  bias1[4], bias2[2], w3v[2];
  #pragma unroll
  for (int Mt = 0; Mt < 4; ++Mt) {
    const float* p = gw1 + (16 * Mt + m) * 32 + 4 * g;
    const f32x4 u0 = *(const f32x4*)p;
    const f32x4 u1 = *(const f32x4*)(p + 16);
    #pragma unroll
    for (int j = 0; j < 4; ++j) { A1[Mt][j] = (__bf16)u0[j]; A1[Mt][j + 4] = (__bf16)u1[j]; }
    bias1[Mt] = *(const f32x4*)(gb1 + 16 * Mt + 4 * g);
  }
  #pragma unroll
  for (int Mt = 0; Mt < 2; ++Mt) {
    #pragma unroll
    for (int s = 0; s < 2; ++s) {
      const float* p = gw2 + (16 * Mt + m) * 64 + 32 * s + 4 * g;
      const f32x4 u0 = *(const f32x4*)p;
      const f32x4 u1 = *(const f32x4*)(p + 16);
      #pragma unroll
      for (int j = 0; j < 4; ++j) { A2[Mt][s][j] = (__bf16)u0[j]; A2[Mt][s][j + 4] = (__bf16)u1[j]; }
    }
    bias2[Mt] = *(const f32x4*)(gb2 + 16 * Mt + 4 * g);
    w3v[Mt]   = *(const f32x4*)(gw3 + 16 * Mt + 4 * g);
  }
  const float b3s = gb3[0];
  const f32x4 zf4 = {0.f, 0.f, 0.f, 0.f};
  const float* base = (t ? gy : gx) + (bh >> 8) * CHW + (bh & 255) * WW;
  unsigned short* xfb = (unsigned short*)(ws + XFB_OFF) + t * 262144 + bh * 512;

  for (int u = wid; u < 32; u += 8) {
    const int w0 = u << 4;
    const float* src = base + w0 + m;

    bf16x8 B1;
    #pragma unroll
    for (int j = 0; j < 8; ++j) {
      const int c = 16 * (j >> 2) + 4 * g + (j & 3);
      B1[j] = (__bf16)fmaxf(src[c * HW], 0.f);
    }
    f32x4 acc1[4];
    #pragma unroll
    for (int Mt = 0; Mt < 4; ++Mt) acc1[Mt] = MFMA16(A1[Mt], B1, zf4);

    bf16x8 B2[2];
    #pragma unroll
    for (int s = 0; s < 2; ++s) {
      #pragma unroll
      for (int j = 0; j < 4; ++j) {
        B2[s][j]     = (__bf16)fmaxf(acc1[2 * s][j]     + bias1[2 * s][j],     0.f);
        B2[s][j + 4] = (__bf16)fmaxf(acc1[2 * s + 1][j] + bias1[2 * s + 1][j], 0.f);
      }
    }
    f32x4 acc2[2];
    #pragma unroll
    for (int Mt = 0; Mt < 2; ++Mt)
      acc2[Mt] = MFMA16(A2[Mt][1], B2[1], MFMA16(A2[Mt][0], B2[0], zf4));

    float s3 = 0.f;
    #pragma unroll
    for (int Mt = 0; Mt < 2; ++Mt)
      #pragma unroll
      for (int r = 0; r < 4; ++r)
        s3 += w3v[Mt][r] * fmaxf(acc2[Mt][r] + bias2[Mt][r], 0.f);
    s3 += __shfl_xor(s3, 16);
    s3 += __shfl_xor(s3, 32);
    const float val = fmaxf(s3 + b3s, 0.f);

    if (lane < 16)
      xfb[w0 + m] = __builtin_bit_cast(unsigned short, (__bf16)val);
  }
}

// ---------------------------------------------------------------- K2
constexpr int CPS    = 1424;                  // hankel copy stride (bytes)
constexpr int K2_HK  = 76800;                 // after full wd image
constexpr int K2_BD  = K2_HK + 8 * CPS;       // 88192: f32[192]
constexpr int K2_LDS = K2_BD + 768;           // 88960 B STATIC

__global__ __launch_bounds__(512)
void panet_corr(const char* __restrict__ ws, float* __restrict__ gout)
{
  __shared__ __align__(16) char lds[K2_LDS];   // STATIC: allocator sees 1
  const int blk  = blockIdx.x;                 // block/CU -> 256-reg budget
  const int dir  = blk >> 9;
  const int bh   = blk & 511;
  const int tid  = threadIdx.x;
  const int lane = tid & 63;
  const int l31  = lane & 31;
  const int h    = lane >> 5;                 // lane half
  const int wid  = tid >> 6;                  // 8 waves, 64 cols each

  const unsigned short* xfbu = (const unsigned short*)(ws + XFB_OFF);
  const unsigned short* hs = xfbu + (dir ? 262144 : 0) + bh * 512;  // hankel src
  const unsigned short* ss = xfbu + (dir ? 0 : 262144) + bh * 512;  // scale src

  // ---- stage wd image + bd; build 8-copy hankel (zeros beyond 511)
  {
    const f32x4* src = (const f32x4*)(ws + WDP_OFF);
    f32x4* dst = (f32x4*)lds;
    #pragma unroll 5
    for (int i = tid; i < 4800; i += 512) dst[i] = src[i];
    if (tid < 192)
      ((float*)(lds + K2_BD))[tid] = ((const float*)(ws + BDP_OFF))[tid];
  }
  for (int e = tid; e < 712; e += 512) {
    #pragma unroll
    for (int c = 0; c < 8; ++c) {
      const int j = e + c;
      unsigned short v = 0;
      if (j <= 511) v = hs[dir ? (511 - j) : j];
      ((unsigned short*)(lds + K2_HK + c * CPS))[e] = v;
    }
  }
  __syncthreads();                             // the ONLY barrier

  // per-lane B bases + scales (2 col-tiles of 32; 64 cols per wave)
  const char* bptr[2]; float sc[2];
  #pragma unroll
  for (int ct = 0; ct < 2; ++ct) {
    const int col = wid * 64 + ct * 32 + l31;
    const int I0  = dir ? (511 - col) : col;
    const int cc  = I0 & 7;
    bptr[ct] = lds + K2_HK + cc * CPS + 2 * (I0 - cc) + 16 * h;
    sc[ct]  = LOG2E * __builtin_bit_cast(float, (unsigned)ss[col] << 16);
  }

  float stS0 = 0.f, stS1 = 0.f, stW0 = 0.f, stW1 = 0.f;

  for (int s = 0; s < 3; ++s) {               // 3 x 64 wd rows
    const char* abase = lds + (64 * s + l31) * 400 + 16 * h;
    f32x16 a00 = {0}, a01 = {0}, a10 = {0}, a11 = {0};
    #pragma unroll 4
    for (int ks = 0; ks < 12; ++ks) {         // K = 12*16 = 192
      const bf16x8 af0 = *(const bf16x8*)(abase + 32 * ks);
      const bf16x8 af1 = *(const bf16x8*)(abase + 12800 + 32 * ks);
      const bf16x8 bf0 = *(const bf16x8*)(bptr[0] + 32 * ks);
      const bf16x8 bf1 = *(const bf16x8*)(bptr[1] + 32 * ks);
      a00 = MFMA32(af0, bf0, a00);
      a01 = MFMA32(af0, bf1, a01);
      a10 = MFMA32(af1, bf0, a10);
      a11 = MFMA32(af1, bf1, a11);
    }

    // bd for this s (hoisted, shared across col-tiles)
    f32x4 bdr0[4], bdr1[4];
    #pragma unroll
    for (int q = 0; q < 4; ++q) {
      bdr0[q] = *(const f32x4*)(lds + K2_BD + (64 * s + 8 * q + 4 * h) * 4);
      bdr1[q] = *(const f32x4*)(lds + K2_BD + (64 * s + 8 * q + 4 * h + 32) * 4);
    }
    const float obase = (float)(64 * s + 4 * h);

    // NO-max softmax accumulation (exp2 domain; logits bounded)
    #pragma unroll
    for (int ct = 0; ct < 2; ++ct) {
      float ls0 = 0.f, ls1 = 0.f, lw0 = 0.f, lw1 = 0.f;
      #pragma unroll
      for (int q = 0; q < 4; ++q) {
        #pragma unroll
        for (int r = 0; r < 4; ++r) {
          const int i = 4 * q + r;
          const float L0 = fmaf(sc[ct], (ct ? a01 : a00)[i], bdr0[q][r]);
          const float L1 = fmaf(sc[ct], (ct ? a11 : a10)[i], bdr1[q][r]);
          const float p0 = __builtin_amdgcn_exp2f(L0);
          const float p1 = __builtin_amdgcn_exp2f(L1);
          const float c  = (float)(r + 8 * q);          // o - obase (rt=0)
          ls0 += p0;  ls1 += p1;
          lw0 = fmaf(c, p0, lw0);
          lw1 = fmaf(c + 32.f, p1, lw1);
        }
      }
      const float ls = ls0 + ls1;
      const float lw = fmaf(obase, ls, lw0 + lw1);
      if (ct == 0) { stS0 += ls; stW0 += lw; }
      else         { stS1 += ls; stW1 += lw; }
    }
  }

  // combine the two lane-halves (o split by h) and write
  float* outp = gout + dir * 262144 + bh * 512;
  #pragma unroll
  for (int ct = 0; ct < 2; ++ct) {
    float sr = ct ? stS1 : stS0;
    float wr = ct ? stW1 : stW0;
    sr += __shfl_xor(sr, 32);
    wr += __shfl_xor(wr, 32);
    if (lane < 32) outp[wid * 64 + ct * 32 + l31] = wr / sr;
  }
}

extern "C" void kernel_launch(void* const* d_in, const int* in_sizes, int n_in,
                              void* d_out, int out_size, void* d_ws, size_t ws_size,
                              hipStream_t stream) {
  const float* x  = (const float*)d_in[0];
  const float* y  = (const float*)d_in[1];
  const float* w1 = (const float*)d_in[2];
  const float* b1 = (const float*)d_in[3];
  const float* w2 = (const float*)d_in[4];
  const float* b2 = (const float*)d_in[5];
  const float* w3 = (const float*)d_in[6];
  const float* b3 = (const float*)d_in[7];
  const float* wd = (const float*)d_in[8];
  const float* bd = (const float*)d_in[9];
  char* ws = (char*)d_ws;

  panet_encode<<<1040, 512, 0, stream>>>(x, y, w1, b1, w2, b2, w3, b3, wd, bd, ws);
  panet_corr<<<1024, 512, 0, stream>>>(ws, (float*)d_out);
}